// Round 3
// baseline (98.917 us; speedup 1.0000x reference)
//
#include <hip/hip_runtime.h>
#include <hip/hip_bf16.h>

#define NG 512
#define IMG_H 192
#define IMG_W 192
#define NPIX (IMG_H * IMG_W)
#define GF 10   // floats per gaussian: u,v,A,B,C,op,beta,r,g,b
#define NCHUNK 8

// Single fused kernel: per-block gaussian preprocessing + depth sort (LDS),
// exact per-strip cull, chunked front-to-back compositing.
// Block = 512 threads = 64 pixels (one 64x1 strip) x 8 depth-chunks.
// Grid = 576 strips (2.25 blocks/CU). Redundant per-block preprocess (~0.5us)
// is cheaper than a separate single-block dispatch + global round-trip.
__global__ __launch_bounds__(512) void splat_kernel(
    const float* __restrict__ means, const float* __restrict__ quats,
    const float* __restrict__ scales, const float* __restrict__ opac,
    const float* __restrict__ colors, const float* __restrict__ betas,
    const float* __restrict__ vm, const float* __restrict__ Ks,
    float* __restrict__ out)
{
    __shared__ float zsh[NG];
    __shared__ __align__(16) float gs[NG * GF];   // depth-sorted gaussian table
    __shared__ int clist[NG];                      // strip-survivor list
    __shared__ float part[NCHUNK * 64 * 5];        // per-(chunk,pixel) partials
    __shared__ int wcnt[NCHUNK];
    __shared__ int woff[NCHUNK + 1];

    const int tid  = threadIdx.x;
    const int lane = tid & 63;
    const int wv   = tid >> 6;

    // ---------------- Phase A: preprocess gaussian `tid` ----------------
    const float Rw[3][3] = {{vm[0], vm[1], vm[2]},
                            {vm[4], vm[5], vm[6]},
                            {vm[8], vm[9], vm[10]}};
    const float tw[3] = {vm[3], vm[7], vm[11]};
    const float fx = Ks[0], cx = Ks[2], fy = Ks[4], cy = Ks[5];

    const int g = tid;
    const float mx = means[g*3+0], my = means[g*3+1], mz = means[g*3+2];
    const float px = Rw[0][0]*mx + Rw[0][1]*my + Rw[0][2]*mz + tw[0];
    const float py = Rw[1][0]*mx + Rw[1][1]*my + Rw[1][2]*mz + tw[1];
    const float pz = Rw[2][0]*mx + Rw[2][1]*my + Rw[2][2]*mz + tw[2];
    zsh[g] = pz;

    float qw = quats[g*4+0], qx = quats[g*4+1], qy = quats[g*4+2], qz = quats[g*4+3];
    const float qn = 1.0f / sqrtf(qw*qw + qx*qx + qy*qy + qz*qz);
    qw *= qn; qx *= qn; qy *= qn; qz *= qn;
    float Rq[3][3];
    Rq[0][0] = 1.f - 2.f*(qy*qy + qz*qz); Rq[0][1] = 2.f*(qx*qy - qw*qz); Rq[0][2] = 2.f*(qx*qz + qw*qy);
    Rq[1][0] = 2.f*(qx*qy + qw*qz); Rq[1][1] = 1.f - 2.f*(qx*qx + qz*qz); Rq[1][2] = 2.f*(qy*qz - qw*qx);
    Rq[2][0] = 2.f*(qx*qz - qw*qy); Rq[2][1] = 2.f*(qy*qz + qw*qx); Rq[2][2] = 1.f - 2.f*(qx*qx + qy*qy);

    const float e0 = expf(scales[g*3+0]);
    const float e1 = expf(scales[g*3+1]);
    const float e2 = expf(scales[g*3+2]);

    float M[3][3];
    #pragma unroll
    for (int i = 0; i < 3; i++) { M[i][0] = Rq[i][0]*e0; M[i][1] = Rq[i][1]*e1; M[i][2] = Rq[i][2]*e2; }
    float c3[3][3];
    #pragma unroll
    for (int i = 0; i < 3; i++)
        #pragma unroll
        for (int k = 0; k < 3; k++)
            c3[i][k] = M[i][0]*M[k][0] + M[i][1]*M[k][1] + M[i][2]*M[k][2];

    float tmpm[3][3];
    #pragma unroll
    for (int i = 0; i < 3; i++)
        #pragma unroll
        for (int k = 0; k < 3; k++)
            tmpm[i][k] = Rw[i][0]*c3[0][k] + Rw[i][1]*c3[1][k] + Rw[i][2]*c3[2][k];
    float S[3][3];
    #pragma unroll
    for (int i = 0; i < 3; i++)
        #pragma unroll
        for (int l = 0; l < 3; l++)
            S[i][l] = tmpm[i][0]*Rw[l][0] + tmpm[i][1]*Rw[l][1] + tmpm[i][2]*Rw[l][2];

    const float tz = fmaxf(pz, 0.01f);
    const float z1 = 1.0f / tz;
    const float j0 = fx*z1, j2 = -fx*px*z1*z1;
    const float j1 = fy*z1, j3 = -fy*py*z1*z1;

    const float cov00 = j0*j0*S[0][0] + 2.f*j0*j2*S[0][2] + j2*j2*S[2][2];
    const float cov01 = j0*j1*S[0][1] + j0*j3*S[0][2] + j2*j1*S[1][2] + j2*j3*S[2][2];
    const float cov11 = j1*j1*S[1][1] + 2.f*j1*j3*S[1][2] + j3*j3*S[2][2];

    const float a = cov00 + 0.3f;
    const float b = cov01;
    const float c = cov11 + 0.3f;
    const float det = a*c - b*b;
    const float u = fx*px*z1 + cx;
    const float v = fy*py*z1 + cy;
    const bool valid = (pz > 0.01f) && (det > 1e-6f);
    const float inv_det = 1.0f / fmaxf(det, 1e-6f);
    float op = 1.0f / (1.0f + expf(-opac[g]));
    if (!valid) op = 0.0f;     // zero opacity == culled everywhere

    __syncthreads();
    int rank = 0;
    #pragma unroll 8
    for (int j = 0; j < NG; j++) {
        const float zj = zsh[j];     // j uniform across wave -> LDS broadcast
        rank += (zj < pz) || (zj == pz && j < g);
    }
    {
        float* dst = gs + rank * GF;
        dst[0] = u;  dst[1] = v;
        dst[2] = c * inv_det;            // Ac
        dst[3] = -b * inv_det;           // Bc
        dst[4] = a * inv_det;            // Cc
        dst[5] = op; dst[6] = betas[g];
        dst[7] = colors[g*3+0]; dst[8] = colors[g*3+1]; dst[9] = colors[g*3+2];
    }
    __syncthreads();

    // ---------------- Phase B: strip cull + composite ----------------
    const int strip = blockIdx.x;          // 576 = 192 rows * 3 strips/row
    const int y  = strip / 3;
    const int x0 = (strip % 3) * 64;
    const float fyp = (float)y + 0.5f;
    const float xlo = (float)x0 + 0.5f;
    const float xhi = (float)x0 + 63.5f;

    {
        const float* gp = gs + tid * GF;
        const float gu = gp[0], gv = gp[1], A = gp[2], B = gp[3], C = gp[4];
        const float gop = gp[5], bt = gp[6];
        const float dy = fyp - gv;
        const float dxlo = xlo - gu, dxhi = xhi - gu;
        float dxs = -B * dy / fmaxf(A, 1e-12f);    // A >= 0.3/det > 0 when op > 0
        dxs = fminf(fmaxf(dxs, dxlo), dxhi);
        float smin = 0.5f * (A * dxs * dxs + C * dy * dy) + B * dxs * dy;
        smin = fmaxf(smin, 1e-8f);
        const float se = (bt == 1.0f) ? smin : powf(smin, bt);
        const float amax = gop * expf(-se);
        const bool keep = amax > (1.0f / 255.0f);

        const unsigned long long m = __ballot(keep);
        if (lane == 0) wcnt[wv] = __popcll(m);
        __syncthreads();
        if (tid == 0) {
            int s = 0;
            #pragma unroll
            for (int k = 0; k < NCHUNK; k++) { woff[k] = s; s += wcnt[k]; }
            woff[NCHUNK] = s;
        }
        __syncthreads();
        if (keep) {
            const int pos = woff[wv] + __popcll(m & ((1ULL << lane) - 1));
            clist[pos] = tid;
        }
    }
    __syncthreads();

    const int total = woff[NCHUNK];
    const int s = (wv * total) >> 3;
    const int e = ((wv + 1) * total) >> 3;

    const float fxp = (float)(x0 + lane) + 0.5f;
    float T = 1.0f, cr = 0.0f, cg = 0.0f, cb = 0.0f, ac = 0.0f;
    for (int i = s; i < e; i++) {
        const float* gp = gs + clist[i] * GF;   // uniform per wave -> broadcast
        const float dx = fxp - gp[0];
        const float dy = fyp - gp[1];
        float sigma = 0.5f * (gp[2]*dx*dx + gp[4]*dy*dy) + gp[3]*dx*dy;
        sigma = fmaxf(sigma, 1e-8f);
        const float bt = gp[6];
        const float se = (bt == 1.0f) ? sigma : powf(sigma, bt);
        float alpha = gp[5] * expf(-se);
        alpha = fminf(alpha, 0.999f);
        if (!(alpha > (1.0f / 255.0f))) alpha = 0.0f;
        const float w = alpha * T;
        cr += w * gp[7]; cg += w * gp[8]; cb += w * gp[9];
        ac += w;
        T *= 1.0f - alpha;
    }

    float* pp = part + (wv * 64 + lane) * 5;   // stride 5: bank-conflict-free
    pp[0] = cr; pp[1] = cg; pp[2] = cb; pp[3] = ac; pp[4] = T;
    __syncthreads();

    if (wv == 0) {
        float Tt = 1.0f, r = 0.0f, gg = 0.0f, bb = 0.0f, aa = 0.0f;
        #pragma unroll
        for (int k = 0; k < NCHUNK; k++) {
            const float* pk = part + (k * 64 + lane) * 5;
            r += Tt * pk[0]; gg += Tt * pk[1]; bb += Tt * pk[2]; aa += Tt * pk[3];
            Tt *= pk[4];
        }
        const int pix = y * IMG_W + x0 + lane;
        out[pix * 3 + 0] = r;
        out[pix * 3 + 1] = gg;
        out[pix * 3 + 2] = bb;
        out[NPIX * 3 + pix] = aa;
    }
}

extern "C" void kernel_launch(void* const* d_in, const int* in_sizes, int n_in,
                              void* d_out, int out_size, void* d_ws, size_t ws_size,
                              hipStream_t stream) {
    const float* means  = (const float*)d_in[0];
    const float* quats  = (const float*)d_in[1];
    const float* scales = (const float*)d_in[2];
    const float* opac   = (const float*)d_in[3];
    const float* colors = (const float*)d_in[4];
    const float* betas  = (const float*)d_in[5];
    const float* vm     = (const float*)d_in[6];
    const float* Ks     = (const float*)d_in[7];
    float* out = (float*)d_out;

    splat_kernel<<<NPIX / 64, 512, 0, stream>>>(
        means, quats, scales, opac, colors, betas, vm, Ks, out);
}

// Round 4
// 75.439 us; speedup vs baseline: 1.3112x; 1.3112x over previous
//
#include <hip/hip_runtime.h>
#include <hip/hip_bf16.h>

#define NG 512
#define IMG_H 192
#define IMG_W 192
#define NPIX (IMG_H * IMG_W)
#define GF 12   // floats per gaussian (padded to 48B for 16B alignment): u,v,A,B,C,op,beta,r,g,b,pad,pad
#define NCHUNK 8

// ---------------- Kernel 1: preprocess + depth rank, 4-way parallel ----------------
// Grid = 4 blocks x 512 threads. Every block computes all 512 view-space z's
// (1 gaussian/thread, trivial VALU). Ranking is split: thread (seg, gl) counts
// rank-partial of owned gaussian g = 128*blk + gl over segment seg (128 z's,
// read as 32 x ds_read_b128). Threads with seg==0 then do the full covariance
// math for the owned gaussian and scatter the record to ws[rank*GF].
__global__ __launch_bounds__(512) void preprocess_kernel(
    const float* __restrict__ means, const float* __restrict__ quats,
    const float* __restrict__ scales, const float* __restrict__ opac,
    const float* __restrict__ colors, const float* __restrict__ betas,
    const float* __restrict__ vm, const float* __restrict__ Ks,
    float* __restrict__ ws)
{
    __shared__ __align__(16) float zsh[NG];
    __shared__ int rpart[4 * 128];      // [seg][gl]

    const int tid = threadIdx.x;
    const int blk = blockIdx.x;
    const int gl  = tid & 127;          // owned gaussian index within block
    const int seg = tid >> 7;           // rank segment 0..3
    const int g   = blk * 128 + gl;     // owned gaussian

    const float Rw[3][3] = {{vm[0], vm[1], vm[2]},
                            {vm[4], vm[5], vm[6]},
                            {vm[8], vm[9], vm[10]}};
    const float tw[3] = {vm[3], vm[7], vm[11]};
    const float fx = Ks[0], cx = Ks[2], fy = Ks[4], cy = Ks[5];

    // ---- all 512 z's (thread tid handles gaussian tid) ----
    {
        const float ax = means[tid*3+0], ay = means[tid*3+1], az = means[tid*3+2];
        zsh[tid] = Rw[2][0]*ax + Rw[2][1]*ay + Rw[2][2]*az + tw[2];
    }
    __syncthreads();

    // ---- segmented rank count (b128 LDS reads) ----
    const float zg = zsh[g];
    int cnt = 0;
    {
        const float4* z4 = (const float4*)(zsh + seg * 128);
        const int jbase = seg * 128;
        #pragma unroll 8
        for (int i = 0; i < 32; i++) {
            const float4 zz = z4[i];
            const int j = jbase + 4 * i;
            cnt += (zz.x < zg) || (zz.x == zg && (j + 0) < g);
            cnt += (zz.y < zg) || (zz.y == zg && (j + 1) < g);
            cnt += (zz.z < zg) || (zz.z == zg && (j + 2) < g);
            cnt += (zz.w < zg) || (zz.w == zg && (j + 3) < g);
        }
    }
    rpart[seg * 128 + gl] = cnt;        // consecutive within wave: conflict-free
    __syncthreads();

    if (seg != 0) return;

    const int rank = rpart[gl] + rpart[128 + gl] + rpart[256 + gl] + rpart[384 + gl];

    // ---- full projection math for owned gaussian ----
    const float mx = means[g*3+0], my = means[g*3+1], mz = means[g*3+2];
    const float px = Rw[0][0]*mx + Rw[0][1]*my + Rw[0][2]*mz + tw[0];
    const float py = Rw[1][0]*mx + Rw[1][1]*my + Rw[1][2]*mz + tw[1];
    const float pz = zg;

    float qw = quats[g*4+0], qx = quats[g*4+1], qy = quats[g*4+2], qz = quats[g*4+3];
    const float qn = 1.0f / sqrtf(qw*qw + qx*qx + qy*qy + qz*qz);
    qw *= qn; qx *= qn; qy *= qn; qz *= qn;
    float Rq[3][3];
    Rq[0][0] = 1.f - 2.f*(qy*qy + qz*qz); Rq[0][1] = 2.f*(qx*qy - qw*qz); Rq[0][2] = 2.f*(qx*qz + qw*qy);
    Rq[1][0] = 2.f*(qx*qy + qw*qz); Rq[1][1] = 1.f - 2.f*(qx*qx + qz*qz); Rq[1][2] = 2.f*(qy*qz - qw*qx);
    Rq[2][0] = 2.f*(qx*qz - qw*qy); Rq[2][1] = 2.f*(qy*qz + qw*qx); Rq[2][2] = 1.f - 2.f*(qx*qx + qy*qy);

    const float e0 = expf(scales[g*3+0]);
    const float e1 = expf(scales[g*3+1]);
    const float e2 = expf(scales[g*3+2]);

    float M[3][3];
    #pragma unroll
    for (int i = 0; i < 3; i++) { M[i][0] = Rq[i][0]*e0; M[i][1] = Rq[i][1]*e1; M[i][2] = Rq[i][2]*e2; }
    float c3[3][3];
    #pragma unroll
    for (int i = 0; i < 3; i++)
        #pragma unroll
        for (int k = 0; k < 3; k++)
            c3[i][k] = M[i][0]*M[k][0] + M[i][1]*M[k][1] + M[i][2]*M[k][2];

    float tmpm[3][3];
    #pragma unroll
    for (int i = 0; i < 3; i++)
        #pragma unroll
        for (int k = 0; k < 3; k++)
            tmpm[i][k] = Rw[i][0]*c3[0][k] + Rw[i][1]*c3[1][k] + Rw[i][2]*c3[2][k];
    float S[3][3];
    #pragma unroll
    for (int i = 0; i < 3; i++)
        #pragma unroll
        for (int l = 0; l < 3; l++)
            S[i][l] = tmpm[i][0]*Rw[l][0] + tmpm[i][1]*Rw[l][1] + tmpm[i][2]*Rw[l][2];

    const float tz = fmaxf(pz, 0.01f);
    const float z1 = 1.0f / tz;
    const float j0 = fx*z1, j2 = -fx*px*z1*z1;
    const float j1 = fy*z1, j3 = -fy*py*z1*z1;

    const float cov00 = j0*j0*S[0][0] + 2.f*j0*j2*S[0][2] + j2*j2*S[2][2];
    const float cov01 = j0*j1*S[0][1] + j0*j3*S[0][2] + j2*j1*S[1][2] + j2*j3*S[2][2];
    const float cov11 = j1*j1*S[1][1] + 2.f*j1*j3*S[1][2] + j3*j3*S[2][2];

    const float a = cov00 + 0.3f;
    const float b = cov01;
    const float c = cov11 + 0.3f;
    const float det = a*c - b*b;
    const float u = fx*px*z1 + cx;
    const float v = fy*py*z1 + cy;
    const bool valid = (pz > 0.01f) && (det > 1e-6f);
    const float inv_det = 1.0f / fmaxf(det, 1e-6f);
    float op = 1.0f / (1.0f + expf(-opac[g]));
    if (!valid) op = 0.0f;     // zero opacity == culled everywhere

    float* dst = ws + rank * GF;    // 48B stride: records stay 16B-aligned
    dst[0]  = u;  dst[1] = v;
    dst[2]  = c * inv_det;           // Ac
    dst[3]  = -b * inv_det;          // Bc
    dst[4]  = a * inv_det;           // Cc
    dst[5]  = op; dst[6] = betas[g];
    dst[7]  = colors[g*3+0]; dst[8] = colors[g*3+1]; dst[9] = colors[g*3+2];
    dst[10] = 0.0f; dst[11] = 0.0f;
}

// ---------------- Kernel 2: strip-culled, chunked compositing ----------------
// Block = 512 threads = 64 pixels (one 64x1 strip) x 8 depth-chunks.
// Grid = 576 strips. LDS ~37 KB -> 4 blocks/CU ceiling, 2.25 avg.
__global__ __launch_bounds__(512) void render_kernel(
    const float* __restrict__ ws, float* __restrict__ out)
{
    __shared__ __align__(16) float gs[NG * GF];   // 24576 B sorted table
    __shared__ int clist[NG];                      // compacted survivor list
    __shared__ float part[NCHUNK * 64 * 5];        // per-(chunk,pixel) partials
    __shared__ int wcnt[NCHUNK];
    __shared__ int woff[NCHUNK + 1];

    const int tid  = threadIdx.x;
    const int lane = tid & 63;
    const int wv   = tid >> 6;      // wave id == chunk id, 0..7

    // stage the gaussian table (float4-vectorized, coalesced)
    {
        const float4* src = (const float4*)ws;
        float4* dst = (float4*)gs;
        #pragma unroll
        for (int i = 0; i < NG * GF / 4 / 512; i++)
            dst[tid + i * 512] = src[tid + i * 512];
    }
    __syncthreads();

    const int strip = blockIdx.x;           // 576 = 192 rows * 3 strips/row
    const int y  = strip / 3;
    const int x0 = (strip % 3) * 64;
    const float fyp = (float)y + 0.5f;
    const float xlo = (float)x0 + 0.5f;
    const float xhi = (float)x0 + 63.5f;

    // ---- exact per-strip cull: max alpha over the strip vs 1/255 ----
    {
        const float* gp = gs + tid * GF;
        const float u = gp[0], v = gp[1], A = gp[2], B = gp[3], C = gp[4];
        const float op = gp[5], bt = gp[6];
        const float dy = fyp - v;
        const float dxlo = xlo - u, dxhi = xhi - u;
        float dxs = -B * dy / fmaxf(A, 1e-12f);     // A > 0 whenever op > 0
        dxs = fminf(fmaxf(dxs, dxlo), dxhi);
        float smin = 0.5f * (A * dxs * dxs + C * dy * dy) + B * dxs * dy;
        smin = fmaxf(smin, 1e-8f);
        const float se = (bt == 1.0f) ? smin : powf(smin, bt);
        const float amax = op * expf(-se);
        const bool keep = amax > (1.0f / 255.0f);

        const unsigned long long m = __ballot(keep);
        if (lane == 0) wcnt[wv] = __popcll(m);
        __syncthreads();
        if (tid == 0) {
            int s = 0;
            #pragma unroll
            for (int k = 0; k < NCHUNK; k++) { woff[k] = s; s += wcnt[k]; }
            woff[NCHUNK] = s;
        }
        __syncthreads();
        if (keep) {
            const int pos = woff[wv] + __popcll(m & ((1ULL << lane) - 1));
            clist[pos] = tid;
        }
    }
    __syncthreads();

    const int total = woff[NCHUNK];
    const int s = (wv * total) >> 3;
    const int e = ((wv + 1) * total) >> 3;

    const float fxp = (float)(x0 + lane) + 0.5f;
    float T = 1.0f, cr = 0.0f, cg = 0.0f, cb = 0.0f, ac = 0.0f;
    for (int i = s; i < e; i++) {
        const float* gp = gs + clist[i] * GF;   // uniform per wave -> broadcast
        const float dx = fxp - gp[0];
        const float dy = fyp - gp[1];
        float sigma = 0.5f * (gp[2]*dx*dx + gp[4]*dy*dy) + gp[3]*dx*dy;
        sigma = fmaxf(sigma, 1e-8f);
        const float bt = gp[6];
        const float se = (bt == 1.0f) ? sigma : powf(sigma, bt);
        float alpha = gp[5] * expf(-se);
        alpha = fminf(alpha, 0.999f);
        if (!(alpha > (1.0f / 255.0f))) alpha = 0.0f;
        const float w = alpha * T;
        cr += w * gp[7]; cg += w * gp[8]; cb += w * gp[9];
        ac += w;
        T *= 1.0f - alpha;
    }

    float* pp = part + (wv * 64 + lane) * 5;   // stride 5: bank-conflict-free
    pp[0] = cr; pp[1] = cg; pp[2] = cb; pp[3] = ac; pp[4] = T;
    __syncthreads();

    // wave 0 combines the 8 chunks front-to-back
    if (wv == 0) {
        float Tt = 1.0f, r = 0.0f, g = 0.0f, b = 0.0f, a = 0.0f;
        #pragma unroll
        for (int k = 0; k < NCHUNK; k++) {
            const float* pk = part + (k * 64 + lane) * 5;
            r += Tt * pk[0]; g += Tt * pk[1]; b += Tt * pk[2]; a += Tt * pk[3];
            Tt *= pk[4];
        }
        const int pix = y * IMG_W + x0 + lane;
        out[pix * 3 + 0] = r;
        out[pix * 3 + 1] = g;
        out[pix * 3 + 2] = b;
        out[NPIX * 3 + pix] = a;
    }
}

extern "C" void kernel_launch(void* const* d_in, const int* in_sizes, int n_in,
                              void* d_out, int out_size, void* d_ws, size_t ws_size,
                              hipStream_t stream) {
    const float* means  = (const float*)d_in[0];
    const float* quats  = (const float*)d_in[1];
    const float* scales = (const float*)d_in[2];
    const float* opac   = (const float*)d_in[3];
    const float* colors = (const float*)d_in[4];
    const float* betas  = (const float*)d_in[5];
    const float* vm     = (const float*)d_in[6];
    const float* Ks     = (const float*)d_in[7];
    float* ws  = (float*)d_ws;
    float* out = (float*)d_out;

    preprocess_kernel<<<4, 512, 0, stream>>>(means, quats, scales, opac, colors, betas, vm, Ks, ws);
    render_kernel<<<NPIX / 64, 512, 0, stream>>>(ws, out);
}